// Round 4
// baseline (326.221 us; speedup 1.0000x reference)
//
#include <hip/hip_runtime.h>
#include <hip/hip_bf16.h>
#include <hip/hip_fp16.h>

#define HCH 4      // heads
#define F   128    // H*C
#define DIN 128
#define HID 128
#define NEG 0.2f
#define L2E 1.4426950408889634f

__device__ __forceinline__ float lrelu(float x){ return fmaxf(x, NEG * x); }

// DPP-based add: v += permute(v), all in VALU pipe (row = 16 lanes on CDNA)
template<int CTRL>
__device__ __forceinline__ float dpp_add(float v){
    int t = __builtin_amdgcn_update_dpp(0, __float_as_int(v), CTRL, 0xF, 0xF, true);
    return v + __int_as_float(t);
}
// full 16-lane (head-group) sum, result in every lane of the group
__device__ __forceinline__ float head_sum(float s){
    s = dpp_add<0xB1>(s);    // quad_perm [1,0,3,2]  (xor 1)
    s = dpp_add<0x4E>(s);    // quad_perm [2,3,0,1]  (xor 2)
    s = dpp_add<0x124>(s);   // row_ror:4
    s = dpp_add<0x128>(s);   // row_ror:8
    return s;
}

// ---- K1: xl_h = half2(x@Wl + bl) ; xr = x@Wr + br  (32 rows / 256 thr) ----
__global__ void k_transform(const float* __restrict__ x,
                            const float* __restrict__ Wl, const float* __restrict__ bl,
                            const float* __restrict__ Wr, const float* __restrict__ br,
                            unsigned* __restrict__ xl_h, float* __restrict__ xr, int N){
    __shared__ float xs[32][DIN];
    const int t  = threadIdx.x;
    const int c2 = t & 63;          // channel pair index: channels 2c2, 2c2+1
    const int rg = t >> 6;          // row group (8 rows each)
    const int base = blockIdx.x * 32;
    {
        const float4* xg = (const float4*)(x + (size_t)base * DIN);
        float4* xsv = (float4*)&xs[0][0];
        #pragma unroll
        for (int q = 0; q < 4; ++q){
            int idx = t + q * 256;  // float4 index within 32x128 tile
            int row = idx >> 5;
            xsv[idx] = (base + row < N) ? xg[idx] : make_float4(0.f,0.f,0.f,0.f);
        }
    }
    __syncthreads();
    const int j0 = 2 * c2;
    float al0[8], al1[8], ar0[8], ar1[8];
    {
        const float bl0 = bl[j0], bl1 = bl[j0 + 1];
        const float br0 = br[j0], br1 = br[j0 + 1];
        #pragma unroll
        for (int r = 0; r < 8; ++r){ al0[r]=bl0; al1[r]=bl1; ar0[r]=br0; ar1[r]=br1; }
    }
    const int r0 = rg * 8;
    const float2* Wl2 = (const float2*)Wl;
    const float2* Wr2 = (const float2*)Wr;
    #pragma unroll 2
    for (int k = 0; k < DIN; ++k){
        const float2 wl = Wl2[k * 64 + c2];
        const float2 wr = Wr2[k * 64 + c2];
        #pragma unroll
        for (int r = 0; r < 8; ++r){
            const float xv = xs[r0 + r][k];
            al0[r] = fmaf(xv, wl.x, al0[r]); al1[r] = fmaf(xv, wl.y, al1[r]);
            ar0[r] = fmaf(xv, wr.x, ar0[r]); ar1[r] = fmaf(xv, wr.y, ar1[r]);
        }
    }
    #pragma unroll
    for (int r = 0; r < 8; ++r){
        const int row = base + r0 + r;
        if (row < N){
            __half2 hl = __floats2half2_rn(al0[r], al1[r]);
            xl_h[(size_t)row * 64 + c2] = *(unsigned*)&hl;
            ((float2*)xr)[(size_t)row * 64 + c2] = make_float2(ar0[r], ar1[r]);
        }
    }
}

// ---- histogram of dst (deg starts at 0; +1 self loop added in scan) ----
__global__ void k_hist(const int* __restrict__ ei, unsigned* __restrict__ deg, int E){
    int t = blockIdx.x * blockDim.x + threadIdx.x;
    if (t < E) atomicAdd(&deg[ei[E + t]], 1u);
}

// ---- per-block sums of (deg+1) ----
__global__ void k_blocksum(const unsigned* __restrict__ deg, unsigned* __restrict__ bsum, int N){
    __shared__ unsigned lds[256];
    int t = threadIdx.x; int idx = blockIdx.x * 256 + t;
    lds[t] = (idx < N) ? (deg[idx] + 1u) : 0u; __syncthreads();
    for (int off = 128; off > 0; off >>= 1){ if (t < off) lds[t] += lds[t + off]; __syncthreads(); }
    if (t == 0) bsum[blockIdx.x] = lds[0];
}

// ---- exclusive scan of block sums (single block, NB<=1024) ----
__global__ void k_spine(const unsigned* __restrict__ bsum, unsigned* __restrict__ spine, int NB){
    __shared__ unsigned lds[1024];
    int t = threadIdx.x;
    unsigned v = (t < NB) ? bsum[t] : 0u;
    lds[t] = v; __syncthreads();
    unsigned acc = v;
    for (int off = 1; off < 1024; off <<= 1){
        unsigned add = (t >= off) ? lds[t - off] : 0u; __syncthreads();
        acc += add; lds[t] = acc; __syncthreads();
    }
    if (t < NB) spine[t] = acc - v;
}

// ---- per-block exclusive scan of (deg+1) + spine -> row_start (+ total) ----
__global__ void k_scan_add(const unsigned* __restrict__ deg, const unsigned* __restrict__ spine,
                           unsigned* __restrict__ row_start, int N){
    __shared__ unsigned lds[256];
    int t = threadIdx.x; int idx = blockIdx.x * 256 + t;
    unsigned v = (idx < N) ? (deg[idx] + 1u) : 0u;
    lds[t] = v; __syncthreads();
    unsigned acc = v;
    for (int off = 1; off < 256; off <<= 1){
        unsigned add = (t >= off) ? lds[t - off] : 0u; __syncthreads();
        acc += add; lds[t] = acc; __syncthreads();
    }
    if (idx < N){
        row_start[idx] = spine[blockIdx.x] + acc - v;
        if (idx == N - 1) row_start[N] = spine[blockIdx.x] + acc;
    }
}

// ---- scatter edges into CSR (slot 0 of each row = self loop, implicit) ----
__global__ void k_scatter(const int* __restrict__ ei, const unsigned* __restrict__ row_start,
                          unsigned* __restrict__ cursor, int* __restrict__ csr_src, int E){
    int t = blockIdx.x * blockDim.x + threadIdx.x;
    if (t >= E) return;
    int dst = ei[E + t];
    unsigned pos = row_start[dst] + 1u + atomicAdd(&cursor[dst], 1u);
    csr_src[pos] = ei[t];
}

// ---- fused per-node: scores + online softmax (ILP4, DPP, fp16 gather) ----
__global__ void k_node(const unsigned* __restrict__ xl_h, const float* __restrict__ xr,
                       const int* __restrict__ csr_src, const unsigned* __restrict__ row_start,
                       const float* __restrict__ att, const float* __restrict__ bias,
                       const int* __restrict__ batch, unsigned* __restrict__ g_bits, int N){
    const int wid  = (int)(((long long)blockIdx.x * blockDim.x + threadIdx.x) >> 6);
    const int lane = threadIdx.x & 63;
    if (wid >= N) return;
    const int i  = wid;
    const int rs = (int)row_start[i];
    const int re = (int)row_start[i + 1];
    const int deg = re - rs;
    const float2 xrv = ((const float2*)xr)[i * 64 + lane];
    float2 atv = ((const float2*)att)[lane];
    atv.x *= L2E; atv.y *= L2E;     // exp2-domain scores

    float m0 = -3.0e38f, d0 = 0.f, ax0 = 0.f, ay0 = 0.f;
    float m1 = -3.0e38f, d1 = 0.f, ax1 = 0.f, ay1 = 0.f;
    float m2 = -3.0e38f, d2 = 0.f, ax2 = 0.f, ay2 = 0.f;
    float m3 = -3.0e38f, d3 = 0.f, ax3 = 0.f, ay3 = 0.f;

    auto proc = [&](unsigned hv, float& m_, float& d_, float& ax_, float& ay_){
        const float2 xlv = __half22float2(*(const __half2*)&hv);
        const float a = lrelu(xlv.x + xrv.x);
        const float b = lrelu(xlv.y + xrv.y);
        float s = fmaf(atv.x, a, atv.y * b);
        s = head_sum(s);                       // 16-lane head sum via DPP
        const float mn = fmaxf(m_, s);
        const float sc = exp2f(m_ - mn);
        const float p  = exp2f(s - mn);
        d_  = fmaf(d_, sc, p);
        ax_ = fmaf(ax_, sc, p * xlv.x);
        ay_ = fmaf(ay_, sc, p * xlv.y);
        m_  = mn;
    };

    if (deg <= 64){
        // lane e holds src of edge e; edge 0 = self loop
        const int my_src = (lane > 0 && lane < deg) ? csr_src[rs + lane] : i;
        int e = 0;
        for (; e + 3 < deg; e += 4){
            const int s0 = __builtin_amdgcn_readlane(my_src, e);
            const int s1 = __builtin_amdgcn_readlane(my_src, e + 1);
            const int s2 = __builtin_amdgcn_readlane(my_src, e + 2);
            const int s3 = __builtin_amdgcn_readlane(my_src, e + 3);
            const unsigned h0 = xl_h[(size_t)s0 * 64 + lane];
            const unsigned h1 = xl_h[(size_t)s1 * 64 + lane];
            const unsigned h2 = xl_h[(size_t)s2 * 64 + lane];
            const unsigned h3 = xl_h[(size_t)s3 * 64 + lane];
            proc(h0, m0, d0, ax0, ay0);
            proc(h1, m1, d1, ax1, ay1);
            proc(h2, m2, d2, ax2, ay2);
            proc(h3, m3, d3, ax3, ay3);
        }
        for (; e < deg; ++e){
            const int s0 = __builtin_amdgcn_readlane(my_src, e);
            proc(xl_h[(size_t)s0 * 64 + lane], m0, d0, ax0, ay0);
        }
    } else {
        // rare fallback (deg > 64): serial, broadcast loads
        proc(xl_h[(size_t)i * 64 + lane], m0, d0, ax0, ay0);
        for (int e = 1; e < deg; ++e){
            const int s0 = csr_src[rs + e];
            proc(xl_h[(size_t)s0 * 64 + lane], m0, d0, ax0, ay0);
        }
    }

    auto merge = [&](float& m_, float& d_, float& ax_, float& ay_,
                     float mo, float do_, float axo, float ayo){
        const float mn = fmaxf(m_, mo);
        const float sa = exp2f(m_ - mn);
        const float sb = exp2f(mo - mn);
        d_  = d_ * sa + do_ * sb;
        ax_ = ax_ * sa + axo * sb;
        ay_ = ay_ * sa + ayo * sb;
        m_  = mn;
    };
    merge(m0, d0, ax0, ay0, m1, d1, ax1, ay1);
    merge(m2, d2, ax2, ay2, m3, d3, ax3, ay3);
    merge(m0, d0, ax0, ay0, m2, d2, ax2, ay2);

    const float inv = 1.f / (d0 + 1e-16f);
    const float2 bz = ((const float2*)bias)[lane];
    const float h0 = fmaxf(fmaf(ax0, inv, bz.x), 0.f);
    const float h1 = fmaxf(fmaf(ay0, inv, bz.y), 0.f);
    const int g = batch[i];
    atomicMax(&g_bits[g * F + 2 * lane],     __float_as_uint(h0));
    atomicMax(&g_bits[g * F + 2 * lane + 1], __float_as_uint(h1));
}

// ---- dueling heads, one block (128 thr) per graph ----
__global__ void k_dueling(const float* __restrict__ g,
                          const float* __restrict__ Wq1, const float* __restrict__ bq1,
                          const float* __restrict__ Wq2, const float* __restrict__ bq2,
                          const float* __restrict__ Wv1, const float* __restrict__ bv1,
                          const float* __restrict__ Wv2, const float* __restrict__ bv2,
                          float* __restrict__ out){
    __shared__ float gs[F], red0[128], red1[128], red2[128];
    const int t = threadIdx.x, gi = blockIdx.x;
    gs[t] = g[gi * F + t];
    __syncthreads();
    float aq = bq1[t], av = bv1[t];
    for (int k = 0; k < F; ++k){
        aq = fmaf(gs[k], Wq1[k * HID + t], aq);
        av = fmaf(gs[k], Wv1[k * HID + t], av);
    }
    aq = aq > 0.f ? aq : 0.f;
    av = av > 0.f ? av : 0.f;
    red0[t] = aq * Wq2[t * 2 + 0];
    red1[t] = aq * Wq2[t * 2 + 1];
    red2[t] = av * Wv2[t];
    __syncthreads();
    for (int off = 64; off > 0; off >>= 1){
        if (t < off){ red0[t] += red0[t + off]; red1[t] += red1[t + off]; red2[t] += red2[t + off]; }
        __syncthreads();
    }
    if (t == 0){
        const float q0 = red0[0] + bq2[0];
        const float q1 = red1[0] + bq2[1];
        const float v  = red2[0] + bv2[0];
        out[gi * 2 + 0] = 0.5f * (q0 - q1) + v;
        out[gi * 2 + 1] = 0.5f * (q1 - q0) + v;
    }
}

extern "C" void kernel_launch(void* const* d_in, const int* in_sizes, int n_in,
                              void* d_out, int out_size, void* d_ws, size_t ws_size,
                              hipStream_t stream) {
    const float* x    = (const float*)d_in[0];
    const float* Wl   = (const float*)d_in[1];
    const float* bl   = (const float*)d_in[2];
    const float* Wr   = (const float*)d_in[3];
    const float* br   = (const float*)d_in[4];
    const float* att  = (const float*)d_in[5];
    const float* bias = (const float*)d_in[6];
    const float* Wq1  = (const float*)d_in[7];
    const float* bq1  = (const float*)d_in[8];
    const float* Wq2  = (const float*)d_in[9];
    const float* bq2  = (const float*)d_in[10];
    const float* Wv1  = (const float*)d_in[11];
    const float* bv1  = (const float*)d_in[12];
    const float* Wv2  = (const float*)d_in[13];
    const float* bv2  = (const float*)d_in[14];
    const int*   ei   = (const int*)d_in[15];
    const int*   batch= (const int*)d_in[16];
    float* out = (float*)d_out;

    const int N  = in_sizes[0] / DIN;
    const int E  = in_sizes[15] / 2;
    const int Et = E + N;
    const int Gg = out_size / 2;
    const int GF = Gg * F;
    const int NB = (N + 255) / 256;

    // workspace layout
    unsigned* xl_h      = (unsigned*)d_ws;                 // N*64 (half2 per pair)
    float*    xr        = (float*)(xl_h + (size_t)N * 64); // N*F
    unsigned* deg       = (unsigned*)(xr + (size_t)N * F); // N      --+
    unsigned* cursor    = deg + N;                         // N        | zeroed
    unsigned* g_bits    = cursor + N;                      // GF     --+
    unsigned* row_start = g_bits + GF;                     // N+1
    unsigned* bsum      = row_start + N + 1;               // NB
    unsigned* spine     = bsum + NB;                       // NB
    int*      csr_src   = (int*)(spine + NB);              // Et

    // K1: linear transforms
    k_transform<<<(N + 31) / 32, 256, 0, stream>>>(x, Wl, bl, Wr, br, xl_h, xr, N);
    // zero deg/cursor/g_bits in one async memset
    hipMemsetAsync(deg, 0, (size_t)(2 * N + GF) * sizeof(unsigned), stream);
    // CSR build
    k_hist<<<(E + 255) / 256, 256, 0, stream>>>(ei, deg, E);
    k_blocksum<<<NB, 256, 0, stream>>>(deg, bsum, N);
    k_spine<<<1, 1024, 0, stream>>>(bsum, spine, NB);
    k_scan_add<<<NB, 256, 0, stream>>>(deg, spine, row_start, N);
    k_scatter<<<(E + 255) / 256, 256, 0, stream>>>(ei, row_start, cursor, csr_src, E);
    // fused per-node GATv2 + pool
    {
        long long thr = (long long)N * 64;
        k_node<<<(unsigned)((thr + 255) / 256), 256, 0, stream>>>(
            xl_h, xr, csr_src, row_start, att, bias, batch, g_bits, N);
    }
    // dueling MLP heads
    k_dueling<<<Gg, 128, 0, stream>>>((const float*)g_bits, Wq1, bq1, Wq2, bq2,
                                      Wv1, bv1, Wv2, bv2, out);
}